// Round 5
// baseline (311.698 us; speedup 1.0000x reference)
//
#include <hip/hip_runtime.h>
#include <hip/hip_fp16.h>
#include <stdint.h>
#include <stddef.h>

// ============================================================================
// HTensorSquare: out[b] = sum_paths alpha * einsum(uvw,ijk,bui,bvj->bwk)
// Irreps in/out: 64x0e + 32x1o + 16x2e (DIM 240), B = 20000.
// 3 fused GEMMs (one per output irrep). A-operand generated in registers with
// packed fp16 math; B = preprocessed fp16 weights (global->VGPR, L2-hot).
// Round 5 (= Round 4 design, pragma placement fixed): pinned 4-waves/EU
// register budget, explicit ping-pong B prefetch chained across K-phases,
// 2-wave blocks with private LDS regions (no __syncthreads), exact 1250x16
// tiling, grouped ds_read_b128 broadcast windows with static extracts.
// ============================================================================

// ---------------------------------------------------------------------------
// Compile-time Clebsch-Gordan machinery (exact port of the reference numpy).
// ---------------------------------------------------------------------------
namespace cg {

struct Cx { double re, im; };
constexpr Cx cmul(Cx a, Cx b){ return { a.re*b.re - a.im*b.im, a.re*b.im + a.im*b.re }; }

constexpr double fact(int n){ double r = 1.0; for (int i = 2; i <= n; ++i) r *= (double)i; return r; }

constexpr double csqrt(double x){
  if (x <= 0.0) return 0.0;
  double r = x > 1.0 ? x : 1.0;
  for (int i = 0; i < 50; ++i) r = 0.5*(r + x/r);
  return r;
}

constexpr double neg1pow(int k){ return (k % 2 == 0) ? 1.0 : -1.0; }

constexpr double su2_cg(int j1,int m1,int j2,int m2,int j3,int m3){
  if (m3 != m1 + m2) return 0.0;
  int vmin = -j1 + j2 + m3;
  if (-j1 + m1 > vmin) vmin = -j1 + m1;
  if (0 > vmin) vmin = 0;
  int vmax = j2 + j3 + m1;
  if (j3 - j1 + j2 < vmax) vmax = j3 - j1 + j2;
  if (j3 + m3 < vmax) vmax = j3 + m3;
  if (vmax < vmin) return 0.0;
  double C = csqrt((2.0*j3 + 1.0)*fact(j3+j1-j2)*fact(j3-j1+j2)*fact(j1+j2-j3)
                   *fact(j3+m3)*fact(j3-m3)
                   /(fact(j1+j2+j3+1)*fact(j1-m1)*fact(j1+m1)*fact(j2-m2)*fact(j2+m2)));
  double S = 0.0;
  for (int v = vmin; v <= vmax; ++v)
    S += neg1pow(v + j2 + m2)*fact(j2+j3+m1-v)*fact(j1-m1+v)
       /(fact(v)*fact(j3-j1+j2-v)*fact(j3+m3-v)*fact(v+j1-j2-m3));
  return C*S;
}

struct QM { Cx v[5][5]; };
constexpr QM qmat(int l){
  QM q{};
  const double r2 = 0.70710678118654752440;
  for (int m = -l; m < 0; ++m){
    q.v[l+m][l-m] = Cx{ r2, 0.0 };
    q.v[l+m][l+m] = Cx{ 0.0, -r2 };
  }
  q.v[l][l] = Cx{ 1.0, 0.0 };
  for (int m = 1; m <= l; ++m){
    double s = neg1pow(m)*r2;
    q.v[l+m][l+m] = Cx{ s, 0.0 };
    q.v[l+m][l-m] = Cx{ 0.0, s };
  }
  Cx ph = (l % 4 == 0) ? Cx{1,0} : (l % 4 == 1) ? Cx{0,-1} : (l % 4 == 2) ? Cx{-1,0} : Cx{0,1};
  QM out{};
  for (int i = 0; i < 5; ++i) for (int j = 0; j < 5; ++j) out.v[i][j] = cmul(ph, q.v[i][j]);
  return out;
}

struct CGT { double v[5][5][5]; };
constexpr CGT cg_tab(int l1,int l2,int l3){
  double C[5][5][5] = {};
  for (int m1 = -l1; m1 <= l1; ++m1)
    for (int m2 = -l2; m2 <= l2; ++m2)
      for (int m3 = -l3; m3 <= l3; ++m3)
        C[l1+m1][l2+m2][l3+m3] = su2_cg(l1,m1,l2,m2,l3,m3);
  QM Q1 = qmat(l1), Q2 = qmat(l2), Q3 = qmat(l3);
  const int n1 = 2*l1+1, n2 = 2*l2+1, n3 = 2*l3+1;
  const double norm = csqrt(2.0*l3 + 1.0);
  CGT R{};
  for (int j = 0; j < n1; ++j)
    for (int l = 0; l < n2; ++l)
      for (int m = 0; m < n3; ++m){
        Cx s{0,0};
        for (int i = 0; i < n1; ++i)
          for (int k = 0; k < n2; ++k)
            for (int n = 0; n < n3; ++n){
              double c = C[i][k][n];
              if (c != 0.0){
                Cx q3c{ Q3.v[n][m].re, -Q3.v[n][m].im };
                Cx t = cmul(cmul(Q1.v[i][j], Q2.v[k][l]), q3c);
                s.re += t.re*c; s.im += t.im*c;
              }
            }
        R.v[j][l][m] = s.re * norm;
      }
  return R;
}

constexpr double tab_sumsq(const CGT& t, int n1, int n2, int n3){
  double s = 0;
  for (int i = 0; i < n1; ++i) for (int j = 0; j < n2; ++j) for (int k = 0; k < n3; ++k)
    s += t.v[i][j][k]*t.v[i][j][k];
  return s;
}

} // namespace cg

constexpr cg::CGT T121 = cg::cg_tab(1,2,1);
constexpr cg::CGT T211 = cg::cg_tab(2,1,1);
constexpr cg::CGT T112 = cg::cg_tab(1,1,2);
constexpr cg::CGT T222 = cg::cg_tab(2,2,2);
constexpr double C000 = cg::cg_tab(0,0,0).v[0][0][0];
constexpr double C011 = cg::cg_tab(0,1,1).v[0][0][0];
constexpr double C022 = cg::cg_tab(0,2,2).v[0][0][0];
constexpr double C101 = cg::cg_tab(1,0,1).v[0][0][0];
constexpr double C110 = cg::cg_tab(1,1,0).v[0][0][0];
constexpr double C220 = cg::cg_tab(2,2,0).v[0][0][0];
constexpr double C202 = cg::cg_tab(2,0,2).v[0][0][0];

static_assert(C000 > 0.99 && C000 < 1.01, "C000");
static_assert(C011 > 1.72 && C011 < 1.74, "C011");
static_assert(C101 > 1.72 && C101 < 1.74, "C101");
static_assert(C022 > 2.22 && C022 < 2.25, "C022");
static_assert(C202 > 2.22 && C202 < 2.25, "C202");
static_assert(C110*C110 > 0.332 && C110*C110 < 0.334, "C110");
static_assert(C220*C220 > 0.199 && C220*C220 < 0.201, "C220");
static_assert(cg::tab_sumsq(T121,3,5,3) > 8.9  && cg::tab_sumsq(T121,3,5,3) < 9.1,  "T121");
static_assert(cg::tab_sumsq(T211,5,3,3) > 8.9  && cg::tab_sumsq(T211,5,3,3) < 9.1,  "T211");
static_assert(cg::tab_sumsq(T112,3,3,5) > 24.9 && cg::tab_sumsq(T112,3,3,5) < 25.1, "T112");
static_assert(cg::tab_sumsq(T222,5,5,5) > 24.9 && cg::tab_sumsq(T222,5,5,5) < 25.1, "T222");

constexpr double A0 = 1.0/cg::csqrt(5376.0);
constexpr double A1 = 1.0/cg::csqrt(5120.0);
constexpr double A2 = 1.0/cg::csqrt(3328.0);

constexpr double S000 = A0*C000, S110 = A0*C110, S220 = A0*C220;
constexpr double S011 = A1*C011, S101 = A1*C101, S121 = A1, S211 = A1;
constexpr double S022 = A2*C022, S112 = A2,      S202 = A2*C202, S222 = A2;

// Workspace layout (fp16 elements): WT0[64][K0], WT1[32][K1], WT2[16][K2]
constexpr int K0 = 5376, K1 = 5120, K2 = 3328;
constexpr int WT1_OFF = 64*K0;              // 344064
constexpr int WT2_OFF = WT1_OFF + 32*K1;    // 507904
constexpr int WT_TOT  = WT2_OFF + 16*K2;    // 561152

// ---------------------------------------------------------------------------
// Device helpers
// ---------------------------------------------------------------------------
typedef _Float16 half8v  __attribute__((ext_vector_type(8)));
typedef _Float16 half4v  __attribute__((ext_vector_type(4)));
typedef _Float16 half2v  __attribute__((ext_vector_type(2)));
typedef float    float4v __attribute__((ext_vector_type(4)));

union Frag { half8v h8; half2v h2[4]; };

__device__ __forceinline__ half2v pfma(half2v a, half2v b, half2v c){
  __half2 r = __hfma2(__builtin_bit_cast(__half2, a),
                      __builtin_bit_cast(__half2, b),
                      __builtin_bit_cast(__half2, c));
  return __builtin_bit_cast(half2v, r);
}
__device__ __forceinline__ half2v pmul(half2v a, half2v b){
  __half2 r = __hmul2(__builtin_bit_cast(__half2, a), __builtin_bit_cast(__half2, b));
  return __builtin_bit_cast(half2v, r);
}
__device__ __forceinline__ half2v pk2(float a, float b){
  return __builtin_bit_cast(half2v, __builtin_amdgcn_cvt_pkrtz(a, b));
}
__device__ __forceinline__ half2v sp1(_Float16 h){ half2v r = { h, h }; return r; }
__device__ __forceinline__ half2v sp8(half8v v, int j){ return sp1(v[j]); }   // j compile-time
__device__ __forceinline__ _Float16 ext24(half8v a, half8v b, half8v c, int e){
  return e < 8 ? a[e] : (e < 16 ? b[e-8] : c[e-16]);                          // e compile-time
}
__device__ __forceinline__ half2v bc2(const _Float16* p){ return sp1(*p); }
__device__ __forceinline__ half8v ldH(const _Float16* p){
  return *reinterpret_cast<const half8v*>(p);
}
__device__ __forceinline__ float4v MF(half8v a, half8v b, float4v c){
  return __builtin_amdgcn_mfma_f32_16x16x32_f16(a, b, c, 0, 0, 0);
}

#define NZ(c) ((c) > 1e-12 || (c) < -1e-12)

constexpr int XS = 248;   // x-tile LDS row stride in halfs (496 B, 16B-aligned rows)

// ---------------------------------------------------------------------------
// Weight preprocessing (unchanged): transposed fp16 weights with scales +
// K-permutations folded in.
// ---------------------------------------------------------------------------
__global__ void tsq_prep(const float* __restrict__ w0, const float* __restrict__ w1,
                         const float* __restrict__ w2, const float* __restrict__ w3,
                         const float* __restrict__ w4, const float* __restrict__ w5,
                         const float* __restrict__ w6, const float* __restrict__ w7,
                         const float* __restrict__ w8, const float* __restrict__ w9,
                         const float* __restrict__ w10, _Float16* __restrict__ wt){
  const int idx = blockIdx.x*256 + threadIdx.x;
  if (idx >= WT_TOT) return;
  float v;
  if (idx < WT1_OFF){
    const int n = idx / K0, k = idx - n*K0;
    if (k < 4096)       v = w0[k*64 + n] * (float)S000;                 // (0,0,0) k=u*64+v
    else if (k < 5120)  v = w4[(k-4096)*64 + n] * (float)S110;          // (1,1,0) k=u*32+v
    else                v = w9[(k-5120)*64 + n] * (float)S220;          // (2,2,0) k=u*16+v
  } else if (idx < WT2_OFF){
    const int j = idx - WT1_OFF;
    const int n = j / K1, k = j - n*K1;
    if (k < 2048){                                  // (0,1,1) reordered k=v*64+u
      const int u = k & 63, vv = k >> 6;
      v = w1[(u*32 + vv)*32 + n] * (float)S011;
    } else if (k < 4096){                           // (1,0,1) natural k=u*64+v
      v = w3[(k-2048)*32 + n] * (float)S101;
    } else if (k < 4608){                           // (1,2,1) reordered k=v*32+u
      const int kl = k - 4096; const int u = kl & 31, vv = kl >> 5;
      v = w6[(u*16 + vv)*32 + n] * (float)S121;
    } else {                                        // (2,1,1) natural k=u*32+v
      v = w8[(k-4608)*32 + n] * (float)S211;
    }
  } else {
    const int j = idx - WT2_OFF;
    const int n = j / K2, k = j - n*K2;
    if (k < 1024){                                  // (0,2,2) reordered k=v*64+u
      const int u = k & 63, vv = k >> 6;
      v = w2[(u*16 + vv)*16 + n] * (float)S022;
    } else if (k < 2048){                           // (1,1,2) natural k=u*32+v
      v = w5[(k-1024)*16 + n] * (float)S112;
    } else if (k < 3072){                           // (2,0,2) natural k=u*64+v
      v = w7[(k-2048)*16 + n] * (float)S202;
    } else {                                        // (2,2,2) natural k=u*16+v
      v = w10[(k-3072)*16 + n] * (float)S222;
    }
  }
  wt[idx] = (_Float16)v;
}

// ---------------------------------------------------------------------------
// Main kernel.  grid (3, 625), block 128 (2 waves).  blockIdx.x = GEMM id.
// Each wave owns its private 16 batch rows (blockIdx.y*2 + waveid) and a
// private LDS region -> no __syncthreads anywhere.  1250x16 = 20000 exactly.
// ---------------------------------------------------------------------------
__global__ __launch_bounds__(128)
__attribute__((amdgpu_waves_per_eu(4, 4)))
void tsq_main(const float* __restrict__ x, const _Float16* __restrict__ wt,
              float* __restrict__ out){
  __shared__ _Float16 lh[2*16*XS];   // 15872 B, split per-wave
  const int g    = blockIdx.x;
  const int tid  = threadIdx.x;
  const int wv   = tid >> 6;
  const int lane = tid & 63;
  const int col  = lane & 15;
  const int tg   = lane >> 4;
  const int b0   = (blockIdx.y*2 + wv) * 16;

  _Float16* region = &lh[wv*16*XS];

  // ---- stage this wave's 16 rows: fp32 global -> fp16 LDS ----
  for (int i = lane; i < 16*60; i += 64){
    const int r = i / 60, c = i - r*60;
    const float4 v = *(reinterpret_cast<const float4*>(x + (size_t)(b0 + r)*240) + c);
    half2v p0 = pk2(v.x, v.y);
    half2v p1 = pk2(v.z, v.w);
    half4v h; h[0]=p0[0]; h[1]=p0[1]; h[2]=p1[0]; h[3]=p1[1];
    *reinterpret_cast<half4v*>(&region[r*XS + c*4]) = h;
  }

  const float4v z4 = {0.f, 0.f, 0.f, 0.f};
  const _Float16* rh = &region[col*XS];   // this lane's x row (m = col)

  // x0 k-windows for both 32-halves of the 64-wide u-range
  Frag x0w[2];
  x0w[0].h8 = ldH(rh + tg*8);
  x0w[1].h8 = ldH(rh + 32 + tg*8);

  if (g == 0){
    // ============ GEMM 0: out[:,0:64], K=5376, N=64 (4 n-tiles) ============
    const _Float16* bp[4];
    #pragma unroll
    for (int nt = 0; nt < 4; ++nt) bp[nt] = wt + (size_t)(nt*16 + col)*K0 + tg*8;
    float4v acc[4];
    #pragma unroll
    for (int nt = 0; nt < 4; ++nt) acc[nt] = z4;

    half8v bfA[4], bfB[4];
    auto ld = [&](int step, half8v* buf){
      #pragma unroll
      for (int nt = 0; nt < 4; ++nt) buf[nt] = ldH(bp[nt] + step*32);
    };
    auto mm = [&](const Frag& af, const half8v* buf){
      #pragma unroll
      for (int nt = 0; nt < 4; ++nt) acc[nt] = MF(af.h8, buf[nt], acc[nt]);
    };
    ld(0, bfA);

    // --- (0,0,0): steps 0..127, u = step>>1, sel = step&1 ---
    for (int blk = 0; blk < 8; ++blk){
      half8v xu8 = ldH(rh + blk*8);
      #pragma unroll
      for (int j = 0; j < 8; ++j){
        const int s = (blk*8 + j)*2;
        const half2v xu2 = sp8(xu8, j);
        ld(s + 1, bfB);
        {
          Frag af;
          #pragma unroll
          for (int tp = 0; tp < 4; ++tp) af.h2[tp] = pmul(xu2, x0w[0].h2[tp]);
          mm(af, bfA);
        }
        ld(s + 2, bfA);   // chains into (1,1,0) at s=126
        {
          Frag af;
          #pragma unroll
          for (int tp = 0; tp < 4; ++tp) af.h2[tp] = pmul(xu2, x0w[1].h2[tp]);
          mm(af, bfB);
        }
      }
    }
    // --- (1,1,0): steps 128..159, u = step-128; A[t] = dot3(x1[u], x1[tg*8+t]) ---
    half2v xP[3][4];
    #pragma unroll
    for (int i = 0; i < 3; ++i)
      #pragma unroll
      for (int tp = 0; tp < 4; ++tp){
        half2v p = { rh[64 + (tg*8 + 2*tp)*3 + i], rh[64 + (tg*8 + 2*tp + 1)*3 + i] };
        xP[i][tp] = p;
      }
    for (int q = 0; q < 4; ++q){
      half8v w0 = ldH(rh + 64 + q*24), w1 = ldH(rh + 64 + q*24 + 8), w2w = ldH(rh + 64 + q*24 + 16);
      #pragma unroll
      for (int j = 0; j < 8; ++j){
        const int s = 128 + q*8 + j;
        const half2v u0 = sp1(ext24(w0,w1,w2w, 3*j)), u1 = sp1(ext24(w0,w1,w2w, 3*j+1)),
                     u2 = sp1(ext24(w0,w1,w2w, 3*j+2));
        half8v* cur = (j & 1) ? bfB : bfA;
        half8v* nxt = (j & 1) ? bfA : bfB;
        ld(s + 1, nxt);   // chains into (2,2,0) at s=159
        Frag af;
        #pragma unroll
        for (int tp = 0; tp < 4; ++tp)
          af.h2[tp] = pfma(xP[2][tp], u2, pfma(xP[1][tp], u1, pmul(xP[0][tp], u0)));
        mm(af, cur);
      }
    }
    // --- (2,2,0): steps 160..167; A[t] = dot5(x2[u], x2[(tg&1)*8+t]) ---
    half2v xQ[5][4];
    #pragma unroll
    for (int i = 0; i < 5; ++i)
      #pragma unroll
      for (int tp = 0; tp < 4; ++tp){
        half2v p = { rh[160 + ((tg&1)*8 + 2*tp)*5 + i], rh[160 + ((tg&1)*8 + 2*tp + 1)*5 + i] };
        xQ[i][tp] = p;
      }
    #pragma unroll
    for (int t8 = 0; t8 < 8; ++t8){
      const int s = 160 + t8;
      half8v* cur = (t8 & 1) ? bfB : bfA;
      half8v* nxt = (t8 & 1) ? bfA : bfB;
      if (t8 < 7) ld(s + 1, nxt);
      const int u = 2*t8 + (tg >> 1);
      half2v xu[5];
      #pragma unroll
      for (int i = 0; i < 5; ++i) xu[i] = bc2(rh + 160 + u*5 + i);
      Frag af;
      #pragma unroll
      for (int tp = 0; tp < 4; ++tp){
        half2v a = pmul(xQ[0][tp], xu[0]);
        #pragma unroll
        for (int i = 1; i < 5; ++i) a = pfma(xQ[i][tp], xu[i], a);
        af.h2[tp] = a;
      }
      mm(af, cur);
    }
    // --- store ---
    #pragma unroll
    for (int r = 0; r < 4; ++r){
      const int b = b0 + tg*4 + r;
      #pragma unroll
      for (int nt = 0; nt < 4; ++nt) out[(size_t)b*240 + nt*16 + col] = acc[nt][r];
    }

  } else if (g == 1){
    // ========== GEMM 1: out[:,64:160] (w*3+kk), K=5120, N=32 ==========
    const _Float16* W = wt + WT1_OFF;
    const _Float16* bp[2];
    #pragma unroll
    for (int nt = 0; nt < 2; ++nt) bp[nt] = W + (size_t)(nt*16 + col)*K1 + tg*8;
    float4v acc[3][2];
    #pragma unroll
    for (int kk = 0; kk < 3; ++kk)
      #pragma unroll
      for (int nt = 0; nt < 2; ++nt) acc[kk][nt] = z4;

    half8v bfA[2], bfB[2];
    auto ld = [&](int step, half8v* buf){
      #pragma unroll
      for (int nt = 0; nt < 2; ++nt) buf[nt] = ldH(bp[nt] + step*32);
    };
    auto mm = [&](const Frag& af, int kk, const half8v* buf){
      #pragma unroll
      for (int nt = 0; nt < 2; ++nt) acc[kk][nt] = MF(af.h8, buf[nt], acc[kk][nt]);
    };
    ld(0, bfA);

    // --- (0,1,1)+(1,0,1): steps 0..127, m = (step>>1)&31, sel = step&1 ---
    for (int h = 0; h < 2; ++h){
      for (int q = 0; q < 4; ++q){
        half8v w0 = ldH(rh + 64 + q*24), w1 = ldH(rh + 64 + q*24 + 8), w2w = ldH(rh + 64 + q*24 + 16);
        #pragma unroll
        for (int j = 0; j < 8; ++j){
          const int s = h*64 + (q*8 + j)*2;
          const half2v c0 = sp1(ext24(w0,w1,w2w, 3*j)), c1 = sp1(ext24(w0,w1,w2w, 3*j+1)),
                       c2 = sp1(ext24(w0,w1,w2w, 3*j+2));
          ld(s + 1, bfB);
          {
            Frag a0, a1, a2;
            #pragma unroll
            for (int tp = 0; tp < 4; ++tp){
              a0.h2[tp] = pmul(c0, x0w[0].h2[tp]);
              a1.h2[tp] = pmul(c1, x0w[0].h2[tp]);
              a2.h2[tp] = pmul(c2, x0w[0].h2[tp]);
            }
            mm(a0, 0, bfA); mm(a1, 1, bfA); mm(a2, 2, bfA);
          }
          ld(s + 2, bfA);   // chains into (1,2,1) at s=126
          {
            Frag a0, a1, a2;
            #pragma unroll
            for (int tp = 0; tp < 4; ++tp){
              a0.h2[tp] = pmul(c0, x0w[1].h2[tp]);
              a1.h2[tp] = pmul(c1, x0w[1].h2[tp]);
              a2.h2[tp] = pmul(c2, x0w[1].h2[tp]);
            }
            mm(a0, 0, bfB); mm(a1, 1, bfB); mm(a2, 2, bfB);
          }
        }
      }
    }
    // pair-transposed x1 window (shared by both CG phases)
    half2v xP[3][4];
    #pragma unroll
    for (int i = 0; i < 3; ++i)
      #pragma unroll
      for (int tp = 0; tp < 4; ++tp){
        half2v p = { rh[64 + (tg*8 + 2*tp)*3 + i], rh[64 + (tg*8 + 2*tp + 1)*3 + i] };
        xP[i][tp] = p;
      }
    // --- (1,2,1): steps 128..143, v = step-128; y[i][kk] = sum_j T121*x2[v][j] ---
    for (int q = 0; q < 2; ++q){
      half8v w5v[5];
      #pragma unroll
      for (int r = 0; r < 5; ++r) w5v[r] = ldH(rh + 160 + q*40 + r*8);
      #pragma unroll
      for (int j = 0; j < 8; ++j){
        const int s = 128 + q*8 + j;
        float xj[5];
        #pragma unroll
        for (int i = 0; i < 5; ++i){ const int e = 5*j + i; xj[i] = (float)w5v[e>>3][e&7]; }
        half8v* cur = (j & 1) ? bfB : bfA;
        half8v* nxt = (j & 1) ? bfA : bfB;
        ld(s + 1, nxt);   // chains into (2,1,1) at s=143
        half2v y2[3][3];
        #pragma unroll
        for (int i = 0; i < 3; ++i)
          #pragma unroll
          for (int kk = 0; kk < 3; ++kk){
            float y = 0.f;
            #pragma unroll
            for (int jj = 0; jj < 5; ++jj){
              const double cd = T121.v[i][jj][kk];
              if (NZ(cd)) y = fmaf((float)cd, xj[jj], y);
            }
            y2[i][kk] = pk2(y, y);
          }
        #pragma unroll
        for (int kk = 0; kk < 3; ++kk){
          Frag af;
          #pragma unroll
          for (int tp = 0; tp < 4; ++tp)
            af.h2[tp] = pfma(xP[2][tp], y2[2][kk], pfma(xP[1][tp], y2[1][kk], pmul(xP[0][tp], y2[0][kk])));
          mm(af, kk, cur);
        }
      }
    }
    // --- (2,1,1): steps 144..159, u = step-144; z[j][kk] = sum_i T211*x2[u][i] ---
    for (int q = 0; q < 2; ++q){
      half8v w5v[5];
      #pragma unroll
      for (int r = 0; r < 5; ++r) w5v[r] = ldH(rh + 160 + q*40 + r*8);
      #pragma unroll
      for (int j = 0; j < 8; ++j){
        const int s = 144 + q*8 + j;
        float xi[5];
        #pragma unroll
        for (int i = 0; i < 5; ++i){ const int e = 5*j + i; xi[i] = (float)w5v[e>>3][e&7]; }
        half8v* cur = (j & 1) ? bfB : bfA;
        half8v* nxt = (j & 1) ? bfA : bfB;
        if (s < 159) ld(s + 1, nxt);
        half2v z2[3][3];
        #pragma unroll
        for (int jj = 0; jj < 3; ++jj)
          #pragma unroll
          for (int kk = 0; kk < 3; ++kk){
            float z = 0.f;
            #pragma unroll
            for (int i = 0; i < 5; ++i){
              const double cd = T211.v[i][jj][kk];
              if (NZ(cd)) z = fmaf((float)cd, xi[i], z);
            }
            z2[jj][kk] = pk2(z, z);
          }
        #pragma unroll
        for (int kk = 0; kk < 3; ++kk){
          Frag af;
          #pragma unroll
          for (int tp = 0; tp < 4; ++tp)
            af.h2[tp] = pfma(xP[2][tp], z2[2][kk], pfma(xP[1][tp], z2[1][kk], pmul(xP[0][tp], z2[0][kk])));
          mm(af, kk, cur);
        }
      }
    }
    // --- store (3 consecutive floats per (b,w)) ---
    #pragma unroll
    for (int r = 0; r < 4; ++r){
      const int b = b0 + tg*4 + r;
      #pragma unroll
      for (int nt = 0; nt < 2; ++nt){
        const int w = nt*16 + col;
        float* o = out + (size_t)b*240 + 64 + 3*w;
        o[0] = acc[0][nt][r]; o[1] = acc[1][nt][r]; o[2] = acc[2][nt][r];
      }
    }

  } else {
    // ========== GEMM 2: out[:,160:240] (w*5+kk), K=3328, N=16 ==========
    const _Float16* W = wt + WT2_OFF;
    const _Float16* bp = W + (size_t)col*K2 + tg*8;
    float4v acc[5];
    #pragma unroll
    for (int kk = 0; kk < 5; ++kk) acc[kk] = z4;

    half8v bfA, bfB;
    bfA = ldH(bp);

    // --- (0,2,2): steps 0..31, v2 = step>>1, sel = step&1; A_kk = x2[v2,kk]*x0w ---
    for (int q = 0; q < 2; ++q){
      half8v w5v[5];
      #pragma unroll
      for (int r = 0; r < 5; ++r) w5v[r] = ldH(rh + 160 + q*40 + r*8);
      #pragma unroll
      for (int j = 0; j < 8; ++j){
        const int s = (q*8 + j)*2;
        half2v xq[5];
        #pragma unroll
        for (int kk = 0; kk < 5; ++kk){ const int e = 5*j + kk; xq[kk] = sp1(w5v[e>>3][e&7]); }
        bfB = ldH(bp + (s+1)*32);
        #pragma unroll
        for (int kk = 0; kk < 5; ++kk){
          Frag af;
          #pragma unroll
          for (int tp = 0; tp < 4; ++tp) af.h2[tp] = pmul(xq[kk], x0w[0].h2[tp]);
          acc[kk] = MF(af.h8, bfA, acc[kk]);
        }
        bfA = ldH(bp + (s+2)*32);   // chains into (1,1,2) at s=30
        #pragma unroll
        for (int kk = 0; kk < 5; ++kk){
          Frag af;
          #pragma unroll
          for (int tp = 0; tp < 4; ++tp) af.h2[tp] = pmul(xq[kk], x0w[1].h2[tp]);
          acc[kk] = MF(af.h8, bfB, acc[kk]);
        }
      }
    }
    // pair-transposed x1 window
    half2v xP[3][4];
    #pragma unroll
    for (int i = 0; i < 3; ++i)
      #pragma unroll
      for (int tp = 0; tp < 4; ++tp){
        half2v p = { rh[64 + (tg*8 + 2*tp)*3 + i], rh[64 + (tg*8 + 2*tp + 1)*3 + i] };
        xP[i][tp] = p;
      }
    // --- (1,1,2): steps 32..63, u = step-32; y[j][kk] = sum_i T112*x1[u][i] ---
    for (int q = 0; q < 4; ++q){
      half8v w0 = ldH(rh + 64 + q*24), w1 = ldH(rh + 64 + q*24 + 8), w2w = ldH(rh + 64 + q*24 + 16);
      #pragma unroll
      for (int j = 0; j < 8; ++j){
        const int s = 32 + q*8 + j;
        float xi[3];
        xi[0] = (float)ext24(w0,w1,w2w, 3*j);
        xi[1] = (float)ext24(w0,w1,w2w, 3*j+1);
        xi[2] = (float)ext24(w0,w1,w2w, 3*j+2);
        const bool odd = (j & 1);
        half8v cur = odd ? bfB : bfA;
        if (odd) bfA = ldH(bp + (s+1)*32); else bfB = ldH(bp + (s+1)*32);  // chains into (2,0,2)
        half2v y2[3][5];
        #pragma unroll
        for (int jj = 0; jj < 3; ++jj)
          #pragma unroll
          for (int kk = 0; kk < 5; ++kk){
            float y = 0.f;
            #pragma unroll
            for (int i = 0; i < 3; ++i){
              const double cd = T112.v[i][jj][kk];
              if (NZ(cd)) y = fmaf((float)cd, xi[i], y);
            }
            y2[jj][kk] = pk2(y, y);
          }
        #pragma unroll
        for (int kk = 0; kk < 5; ++kk){
          Frag af;
          #pragma unroll
          for (int tp = 0; tp < 4; ++tp)
            af.h2[tp] = pfma(xP[2][tp], y2[2][kk], pfma(xP[1][tp], y2[1][kk], pmul(xP[0][tp], y2[0][kk])));
          acc[kk] = MF(af.h8, cur, acc[kk]);
        }
      }
    }
    // --- (2,0,2): steps 64..95, u2 = (step-64)>>1, sel; A_kk = x2[u2,kk]*x0w ---
    for (int q = 0; q < 2; ++q){
      half8v w5v[5];
      #pragma unroll
      for (int r = 0; r < 5; ++r) w5v[r] = ldH(rh + 160 + q*40 + r*8);
      #pragma unroll
      for (int j = 0; j < 8; ++j){
        const int s = 64 + (q*8 + j)*2;
        half2v xq[5];
        #pragma unroll
        for (int kk = 0; kk < 5; ++kk){ const int e = 5*j + kk; xq[kk] = sp1(w5v[e>>3][e&7]); }
        bfB = ldH(bp + (s+1)*32);
        #pragma unroll
        for (int kk = 0; kk < 5; ++kk){
          Frag af;
          #pragma unroll
          for (int tp = 0; tp < 4; ++tp) af.h2[tp] = pmul(xq[kk], x0w[0].h2[tp]);
          acc[kk] = MF(af.h8, bfA, acc[kk]);
        }
        bfA = ldH(bp + (s+2)*32);   // chains into (2,2,2) at s=94
        #pragma unroll
        for (int kk = 0; kk < 5; ++kk){
          Frag af;
          #pragma unroll
          for (int tp = 0; tp < 4; ++tp) af.h2[tp] = pmul(xq[kk], x0w[1].h2[tp]);
          acc[kk] = MF(af.h8, bfB, acc[kk]);
        }
      }
    }
    // --- (2,2,2): steps 96..103; peel last prefetch (end of wt buffer) ---
    half2v xQ[5][4];
    #pragma unroll
    for (int jj = 0; jj < 5; ++jj)
      #pragma unroll
      for (int tp = 0; tp < 4; ++tp){
        half2v p = { rh[160 + ((tg&1)*8 + 2*tp)*5 + jj], rh[160 + ((tg&1)*8 + 2*tp + 1)*5 + jj] };
        xQ[jj][tp] = p;
      }
    #pragma unroll
    for (int t8 = 0; t8 < 8; ++t8){
      const int s = 96 + t8;
      const bool odd = (t8 & 1);
      half8v cur = odd ? bfB : bfA;
      if (t8 < 7){ if (odd) bfA = ldH(bp + (s+1)*32); else bfB = ldH(bp + (s+1)*32); }
      const int u = 2*t8 + (tg >> 1);
      float xi[5];
      #pragma unroll
      for (int i = 0; i < 5; ++i) xi[i] = (float)rh[160 + u*5 + i];
      half2v w2t[5][5];
      #pragma unroll
      for (int jj = 0; jj < 5; ++jj)
        #pragma unroll
        for (int kk = 0; kk < 5; ++kk){
          float w = 0.f;
          #pragma unroll
          for (int i = 0; i < 5; ++i){
            const double cd = T222.v[i][jj][kk];
            if (NZ(cd)) w = fmaf((float)cd, xi[i], w);
          }
          w2t[jj][kk] = pk2(w, w);
        }
      #pragma unroll
      for (int kk = 0; kk < 5; ++kk){
        Frag af;
        #pragma unroll
        for (int tp = 0; tp < 4; ++tp){
          half2v a = pmul(xQ[0][tp], w2t[0][kk]);
          #pragma unroll
          for (int jj = 1; jj < 5; ++jj) a = pfma(xQ[jj][tp], w2t[jj][kk], a);
          af.h2[tp] = a;
        }
        acc[kk] = MF(af.h8, cur, acc[kk]);
      }
    }
    // --- store (5 consecutive floats per (b,w)) ---
    #pragma unroll
    for (int r = 0; r < 4; ++r){
      const int b = b0 + tg*4 + r;
      float* o = out + (size_t)b*240 + 160 + 5*col;
      o[0] = acc[0][r]; o[1] = acc[1][r]; o[2] = acc[2][r];
      o[3] = acc[3][r]; o[4] = acc[4][r];
    }
  }
}

// ---------------------------------------------------------------------------
extern "C" void kernel_launch(void* const* d_in, const int* in_sizes, int n_in,
                              void* d_out, int out_size, void* d_ws, size_t ws_size,
                              hipStream_t stream){
  (void)in_sizes; (void)n_in; (void)out_size; (void)ws_size;
  const float* x = (const float*)d_in[0];
  const float* w[11];
  for (int i = 0; i < 11; ++i) w[i] = (const float*)d_in[1 + i];
  _Float16* wt = (_Float16*)d_ws;
  float* out = (float*)d_out;

  tsq_prep<<<(WT_TOT + 255)/256, 256, 0, stream>>>(w[0], w[1], w[2], w[3], w[4], w[5],
                                                   w[6], w[7], w[8], w[9], w[10], wt);
  dim3 gm(3, 625);
  tsq_main<<<gm, 128, 0, stream>>>(x, wt, out);
}